// Round 9
// baseline (282.387 us; speedup 1.0000x reference)
//
#include <hip/hip_runtime.h>
#include <hip/hip_bf16.h>

// Problem constants (fixed by reference)
#define T_TOTAL 786432
#define N_IN 50
#define K_FEAT 400
#define C_OUT 10
#define NSEG 32768                  // T/24 pooled segments

// ---- workspace layout ----
// [0,      51200)  : w1f   — W1 16x16 MFMA B-frags (fallback kernel)
// [51200,  83200)  : w2t   — W2 transposed floats (fallback epilogue)
// [98304,  151552) : w1f32 — W1 32x32 MFMA B-frags: frag fi=(ft*4+kt)*64+lane, 8 shorts
// [163840, 183808) : w2p   — W2 f32 blob: w2p[(ft*32+m32)*12 + c] = W2[c][32*ft+m32]
//                            (all 10 classes per feat, padded to 12; h-independent)
#define W1F_TASKS (25 * 2 * 64)        // 3200
#define W2T_OFF_BYTES 51200
#define W2T_FLOATS (25 * 320)          // 8000
#define W1F32_OFF_BYTES 98304
#define W1F32_TASKS (13 * 4 * 64)      // 3328
#define W2P_OFF_BYTES 163840
#define W2P_TASKS (13 * 32)            // 416, each writes 12 floats
#define PREP_TASKS (W1F_TASKS + W2T_FLOATS + W1F32_TASKS + W2P_TASKS)
#define WS_NEEDED (W2P_OFF_BYTES + (size_t)W2P_TASKS * 12 * 4)

typedef __bf16 bfx8 __attribute__((ext_vector_type(8)));
typedef short  s16x8 __attribute__((ext_vector_type(8)));
typedef float  f32x2 __attribute__((ext_vector_type(2)));
typedef float  f32x4 __attribute__((ext_vector_type(4)));
typedef float  f32x16 __attribute__((ext_vector_type(16)));

static __device__ __forceinline__ short f2bf(float f) {
    union { float f; unsigned u; } v; v.f = f;
    unsigned r = v.u + 0x7fffu + ((v.u >> 16) & 1u);
    return (short)(r >> 16);
}

// ================= prep: build fragment-ordered weight blobs =================
__global__ void prep_kernel(const float* __restrict__ W1,
                            const float* __restrict__ W2,
                            short* __restrict__ w1f, float* __restrict__ w2t,
                            short* __restrict__ w1f32, float* __restrict__ w2p)
{
    const int gid = blockIdx.x * blockDim.x + threadIdx.x;
    if (gid < W1F_TASKS) {
        const int lane = gid & 63;
        const int s    = (gid >> 6) & 1;
        const int tile = gid >> 7;          // 0..24
        const int m16  = lane & 15;
        const int quad = lane >> 4;
        const float* row = W1 + (tile * 16 + m16) * N_IN;
        s16x8 v;
        #pragma unroll
        for (int j = 0; j < 8; ++j) {
            const int n = s * 32 + quad * 8 + j;
            v[j] = (n < N_IN) ? f2bf(row[n]) : (short)0;
        }
        *(s16x8*)&w1f[gid * 8] = v;
    } else if (gid < W1F_TASKS + W2T_FLOATS) {
        const int i   = gid - W1F_TASKS;    // i = j*320 + tid
        const int j   = i / 320;
        const int tid = i - j * 320;
        const int o    = tid >> 4;
        const int part = tid & 15;
        const int seg  = (o >= 10) ? 1 : 0;
        const int cls  = o - seg * 10;
        w2t[i] = W2[cls * K_FEAT + part * 25 + j];
    } else if (gid < W1F_TASKS + W2T_FLOATS + W1F32_TASKS) {
        // w1f32: B-frag for 32x32x16 GEMM1. B[k][n]: lane l holds
        // B[k=(l>>5)*8+j][n=l&31] = W1[feat=ft*32+(l&31)][col=kt*16+(l>>5)*8+j]
        const int i    = gid - W1F_TASKS - W2T_FLOATS;   // (ft*4+kt)*64+lane
        const int lane = i & 63;
        const int fi   = i >> 6;            // 0..51
        const int ft   = fi >> 2;           // 0..12
        const int kt   = fi & 3;            // 0..3
        const int feat = ft * 32 + (lane & 31);
        const int cbase = kt * 16 + (lane >> 5) * 8;
        s16x8 v;
        #pragma unroll
        for (int j = 0; j < 8; ++j) {
            const int col = cbase + j;
            v[j] = (feat < K_FEAT && col < N_IN) ? f2bf(W1[feat * N_IN + col])
                                                 : (short)0;
        }
        *(s16x8*)&w1f32[i * 8] = v;
    } else if (gid < PREP_TASKS) {
        // w2p: per-feat f32 W2 slice: all 10 classes for feat = 32*ft + m32,
        // padded to 12 floats for aligned float4 loads (h-independent).
        const int i    = gid - W1F_TASKS - W2T_FLOATS - W1F32_TASKS; // ft*32+m32
        const int ft   = i >> 5;            // 0..12
        const int m32  = i & 31;
        const int feat = 32 * ft + m32;
        float v[12];
        #pragma unroll
        for (int c = 0; c < 12; ++c)
            v[c] = (c < C_OUT && feat < K_FEAT) ? W2[c * K_FEAT + feat] : 0.f;
        float4* dst = (float4*)&w2p[(size_t)i * 12];
        dst[0] = make_float4(v[0], v[1], v[2], v[3]);
        dst[1] = make_float4(v[4], v[5], v[6], v[7]);
        dst[2] = make_float4(v[8], v[9], v[10], v[11]);
    }
}

// ========== fused phase 1, rt-split: 3 waves/block, one rt (32 rows) each ====
// Round-9: CONCURRENCY play. Rounds 0-8 pinned at 94-100 us across six
// structures with ~3 waves/SIMD and a long per-wave serial chain (13 ft x
// {4-MFMA chain -> pool -> epilogue}); busy ~= 3 x 35% -> latency-bound on
// too-few waves. Split each 96-row chunk across 3 waves (wave wv = rt wv):
// Af 48->16 regs, oacc 40->20, per-ft CP cut ~3x, waves 8192->24576.
// (192,5): 102-reg budget (safe from the 128-cap cliff of rounds 1/5/6),
// ~18 waves/CU resident (~56% occ vs 29%). rt->segment mapping is the
// proven per-rt c0/c1 split: c0 -> seg wv, c1 -> seg wv+1; partials combine
// via 240 B LDS. Pool groups, deferred w2p-12 epilogue, 6-stride xor reduce
// all round-8-verified. Spill tripwire: WRITE_SIZE ~1.28 MB.
__global__ __launch_bounds__(192, 5) void phase1_rt(
    const float* __restrict__ x, const short* __restrict__ w1f32,
    const float* __restrict__ w2p, float* __restrict__ out)
{
    __shared__ __align__(16) short xs[4800];   // one 96x50 bf16 chunk
    __shared__ float part[3][20];              // per-wave {c0,c1} x 10 classes
    const int tid  = threadIdx.x;
    const int lane = tid & 63;
    const int wv   = tid >> 6;          // 0..2 == rt of this wave
    const int m32  = lane & 31;
    const int h    = lane >> 5;
    const int chunk = blockIdx.x;       // 0..8191
    const s16x8* wf = (const s16x8*)w1f32;

    auto loadB = [&](s16x8* B, int ft) {
        #pragma unroll
        for (int kt = 0; kt < 4; ++kt) B[kt] = wf[(ft * 4 + kt) * 64 + lane];
    };

    // prefetch ft=0 weights before staging (arrive under the x stream)
    s16x8 Bc[4];
    loadB(Bc, 0);

    // ---- stage 96x50 f32 -> bf16 LDS cooperatively (3 waves, coalesced) ----
    {
        const float* xg = x + (size_t)chunk * 4800;
        #pragma unroll
        for (int i = 0; i < 7; ++i) {
            const int q = 192 * i + tid;        // float4 index, 1200 total
            if (i < 6 || tid < 48) {
                const float4 v = *(const float4*)(xg + 4 * q);
                int lo, hi;
                asm("v_cvt_pk_bf16_f32 %0, %1, %2" : "=v"(lo) : "v"(v.x), "v"(v.y));
                asm("v_cvt_pk_bf16_f32 %0, %1, %2" : "=v"(hi) : "v"(v.z), "v"(v.w));
                int2 pk; pk.x = lo; pk.y = hi;
                *(int2*)&xs[4 * q] = pk;        // ds_write_b64, linear
            }
        }
    }
    __syncthreads();    // all 3 waves consume the shared slab

    // ---- A fragments for THIS wave's rt (bank-conflict-free b32 reads) ----
    // A[m=l&31][k=(l>>5)*8+j]; k = kt*16 + 8h + j; rows 32*wv .. 32*wv+31
    s16x8 Af[4];
    {
        const int row = 32 * wv + m32;
        const short* rp = xs + row * 50 + 8 * h;
        #pragma unroll
        for (int kt = 0; kt < 3; ++kt) {
            int d0 = *(const int*)(rp + 16 * kt + 0);
            int d1 = *(const int*)(rp + 16 * kt + 2);
            int d2 = *(const int*)(rp + 16 * kt + 4);
            int d3 = *(const int*)(rp + 16 * kt + 6);
            int4 di = {d0, d1, d2, d3};
            Af[kt] = __builtin_bit_cast(s16x8, di);
        }
        // kt=3: only cols 48,49 exist (h==0, j=0,1); rest must be exact zero
        int dt = 0;
        if (h == 0) dt = *(const int*)(xs + row * 50 + 48);
        int4 di3 = {dt, 0, 0, 0};
        Af[3] = __builtin_bit_cast(s16x8, di3);
    }

    // oacc[slot][k]: per-lane PARTIAL logits. slot 0 = c0 (-> seg wv),
    // slot 1 = c1 (-> seg wv+1); component p of oacc[slot][k] is class 2k+p.
    f32x2 oacc[2][5];
    #pragma unroll
    for (int s = 0; s < 2; ++s)
        #pragma unroll
        for (int k = 0; k < 5; ++k) { oacc[s][k][0] = 0.f; oacc[s][k][1] = 0.f; }

    const f32x2 z2 = {0.f, 0.f};

    // ---- rolled ft-loop over 13 feature tiles, 4 MFMA each ----
    for (int ft = 0; ft < 13; ++ft) {
        // W2 slice (all 10 classes for feat = 32*ft + m32), issued early
        const float* wl = w2p + (size_t)(ft * 32 + m32) * 12;
        const float4 wa = *(const float4*)wl;
        const float4 wb = *(const float4*)(wl + 4);
        const float2 wc2 = *(const float2*)(wl + 8);

        f32x16 acc;
        #pragma unroll
        for (int r = 0; r < 16; ++r) acc[r] = 0.f;
        __builtin_amdgcn_s_setprio(1);
        #pragma unroll
        for (int kt = 0; kt < 4; ++kt)
            acc = __builtin_amdgcn_mfma_f32_32x32x16_bf16(
                    __builtin_bit_cast(bfx8, Af[kt]),
                    __builtin_bit_cast(bfx8, Bc[kt]), acc, 0, 0, 0);
        __builtin_amdgcn_s_setprio(0);
        // prefetch next ft's B-frags (L2 latency rides under pool+epilogue
        // of this wave and the other ~17 resident waves)
        if (ft < 12) loadB(Bc, ft + 1);

        // relu + per-reg-group sums. C/D: row = (reg&3)+8*(reg>>2)+4h+32*wv,
        // col = m32. Reg-group g = reg>>2 spans rows {4g*2..}; segment
        // boundary falls between groups (proven mapping):
        //   wv=0: groups 0..2 -> seg0 (c0), group 3 -> seg1 (c1)
        //   wv=1: groups 0..1 -> seg1 (c0), groups 2..3 -> seg2 (c1)
        //   wv=2: group  0    -> seg2 (c0), groups 1..3 -> seg3 (c1)
        f32x2 gs[4];
        #pragma unroll
        for (int g = 0; g < 4; ++g) {
            f32x2 a0; a0[0] = acc[4 * g + 0]; a0[1] = acc[4 * g + 1];
            f32x2 a1; a1[0] = acc[4 * g + 2]; a1[1] = acc[4 * g + 3];
            gs[g] = __builtin_elementwise_max(a0, z2)
                  + __builtin_elementwise_max(a1, z2);
        }
        f32x2 cv0, cv1;
        if (wv == 0)      { cv0 = gs[0] + gs[1] + gs[2]; cv1 = gs[3]; }
        else if (wv == 1) { cv0 = gs[0] + gs[1];         cv1 = gs[2] + gs[3]; }
        else              { cv0 = gs[0];                 cv1 = gs[1] + gs[2] + gs[3]; }
        const float c0 = cv0[0] + cv0[1];
        const float c1 = cv1[0] + cv1[1];

        // deferred second GEMM on partials (round-8 proven; no shuffles)
        f32x2 wp[5];
        wp[0][0] = wa.x; wp[0][1] = wa.y;
        wp[1][0] = wa.z; wp[1][1] = wa.w;
        wp[2][0] = wb.x; wp[2][1] = wb.y;
        wp[3][0] = wb.z; wp[3][1] = wb.w;
        wp[4][0] = wc2.x; wp[4][1] = wc2.y;
        const f32x2 c0v = {c0, c0}, c1v = {c1, c1};
        #pragma unroll
        for (int k = 0; k < 5; ++k) {
            oacc[0][k] = __builtin_elementwise_fma(c0v, wp[k], oacc[0][k]);
            oacc[1][k] = __builtin_elementwise_fma(c1v, wp[k], oacc[1][k]);
        }
    }

    // ---- one deferred reduction: strides 1..16 sum the 32 feat-columns of
    // each half; stride 32 merges the two halves' row-partials ----
    #pragma unroll
    for (int s = 0; s < 2; ++s)
        #pragma unroll
        for (int k = 0; k < 5; ++k)
            #pragma unroll
            for (int p = 0; p < 2; ++p) {
                float v = oacc[s][k][p];
                v += __shfl_xor(v, 1);
                v += __shfl_xor(v, 2);
                v += __shfl_xor(v, 4);
                v += __shfl_xor(v, 8);
                v += __shfl_xor(v, 16);
                v += __shfl_xor(v, 32);
                oacc[s][k][p] = v;
            }
    if (lane == 0) {
        #pragma unroll
        for (int s = 0; s < 2; ++s)
            #pragma unroll
            for (int k = 0; k < 5; ++k)
                #pragma unroll
                for (int p = 0; p < 2; ++p)
                    part[wv][s * 10 + 2 * k + p] = oacc[s][k][p];
    }
    __syncthreads();

    // ---- combine: seg s = wave s's c0 + wave (s-1)'s c1 ----
    if (tid < 40) {
        const int s = tid / 10;
        const int c = tid - s * 10;
        float v = 0.f;
        if (s < 3) v += part[s][c];
        if (s > 0) v += part[s - 1][10 + c];
        out[(size_t)(chunk * 4 + s) * C_OUT + c] = v * (1.0f / 24.0f);
    }
}

// ================= fallback (round-3 fused kernel, verbatim) ================
#define FB_CPB 4
#define FB_NTHREADS 320
#define FB_XS_STRIDE 72
#define FB_XS_ROWS (FB_CPB * 48)

__global__ __launch_bounds__(FB_NTHREADS) void classifier_fb(
    const float* __restrict__ x, const short* __restrict__ w1f,
    const float* __restrict__ w2t, float* __restrict__ out)
{
    __shared__ short xs[FB_XS_ROWS * FB_XS_STRIDE];
    __shared__ float pooled[2 * K_FEAT];

    const int tid  = threadIdx.x;
    const int wave = tid >> 6;
    const int lane = tid & 63;
    const int m16  = lane & 15;
    const int quad = lane >> 4;

    {
        const float* xb = x + (size_t)blockIdx.x * (FB_XS_ROWS * N_IN);
        #pragma unroll
        for (int it = 0; it < (FB_XS_ROWS * 25) / FB_NTHREADS; ++it) {
            const int i = tid + it * FB_NTHREADS;
            const int r = i / 25;
            const int c2 = i - r * 25;
            const float2 v = *(const float2*)(xb + 2 * i);
            const int packed = (unsigned short)f2bf(v.x) |
                               ((unsigned)(unsigned short)f2bf(v.y) << 16);
            *(int*)&xs[r * FB_XS_STRIDE + 2 * c2] = packed;
        }
        for (int i = tid; i < FB_XS_ROWS * 7; i += FB_NTHREADS) {
            const int r = i / 7;
            const int c = 50 + 2 * (i - r * 7);
            *(int*)&xs[r * FB_XS_STRIDE + c] = 0;
        }
    }

    s16x8 bfrag[5][2];
    {
        const s16x8* wf = (const s16x8*)w1f;
        #pragma unroll
        for (int t = 0; t < 5; ++t)
            #pragma unroll
            for (int s = 0; s < 2; ++s)
                bfrag[t][s] = wf[((wave * 5 + t) * 2 + s) * 64 + lane];
    }

    const int o    = tid >> 4;
    const int part = tid & 15;
    const int segO = (o >= 10) ? 1 : 0;
    const int cls  = o - segO * 10;
    float w2r[25];
    #pragma unroll
    for (int j = 0; j < 25; ++j) w2r[j] = w2t[j * FB_NTHREADS + tid];

    __syncthreads();

    for (int ciq = 0; ciq < FB_CPB; ++ciq) {
        s16x8 a[3][2];
        #pragma unroll
        for (int r = 0; r < 3; ++r) {
            const short* arow =
                &xs[(ciq * 48 + r * 16 + m16) * FB_XS_STRIDE + quad * 8];
            a[r][0] = *(const s16x8*)(arow);
            a[r][1] = *(const s16x8*)(arow + 32);
        }
        #pragma unroll
        for (int t = 0; t < 5; ++t) {
            float c0 = 0.f, c1 = 0.f;
            #pragma unroll
            for (int r = 0; r < 3; ++r) {
                f32x4 acc = {0.f, 0.f, 0.f, 0.f};
                acc = __builtin_amdgcn_mfma_f32_16x16x32_bf16(
                        __builtin_bit_cast(bfx8, a[r][0]),
                        __builtin_bit_cast(bfx8, bfrag[t][0]), acc, 0, 0, 0);
                acc = __builtin_amdgcn_mfma_f32_16x16x32_bf16(
                        __builtin_bit_cast(bfx8, a[r][1]),
                        __builtin_bit_cast(bfx8, bfrag[t][1]), acc, 0, 0, 0);
                const float s = fmaxf(acc[0], 0.f) + fmaxf(acc[1], 0.f)
                              + fmaxf(acc[2], 0.f) + fmaxf(acc[3], 0.f);
                if (r * 4 + quad < 6) c0 += s; else c1 += s;
            }
            c0 += __shfl_xor(c0, 16); c0 += __shfl_xor(c0, 32);
            c1 += __shfl_xor(c1, 16); c1 += __shfl_xor(c1, 32);
            if (quad == 0) {
                const int feat = (wave * 5 + t) * 16 + m16;
                pooled[feat] = c0;
                pooled[K_FEAT + feat] = c1;
            }
        }
        __syncthreads();

        float sum = 0.f;
        const float* pv = &pooled[segO * K_FEAT + part * 25];
        #pragma unroll
        for (int j = 0; j < 25; ++j) sum += pv[j] * w2r[j];
        sum += __shfl_down(sum, 8, 16);
        sum += __shfl_down(sum, 4, 16);
        sum += __shfl_down(sum, 2, 16);
        sum += __shfl_down(sum, 1, 16);
        if (part == 0) {
            const int chunk = blockIdx.x * FB_CPB + ciq;
            out[(chunk * 2 + segO) * C_OUT + cls] = sum * (1.0f / 24.0f);
        }
        __syncthreads();
    }
}

// ============================== launch ======================================
extern "C" void kernel_launch(void* const* d_in, const int* in_sizes, int n_in,
                              void* d_out, int out_size, void* d_ws, size_t ws_size,
                              hipStream_t stream) {
    const float* x  = (const float*)d_in[0];
    const float* W1 = (const float*)d_in[1];
    const float* W2 = (const float*)d_in[2];
    float* out = (float*)d_out;

    short* w1f   = (short*)d_ws;
    float* w2t   = (float*)((char*)d_ws + W2T_OFF_BYTES);
    short* w1f32 = (short*)((char*)d_ws + W1F32_OFF_BYTES);
    float* w2p   = (float*)((char*)d_ws + W2P_OFF_BYTES);

    prep_kernel<<<(PREP_TASKS + 255) / 256, 256, 0, stream>>>(W1, W2, w1f, w2t,
                                                              w1f32, w2p);

    if (ws_size >= WS_NEEDED) {
        phase1_rt<<<8192, 192, 0, stream>>>(x, w1f32, w2p, out);
    } else {
        classifier_fb<<<4096, FB_NTHREADS, 0, stream>>>(x, w1f, w2t, out);
    }
}